// Round 4
// baseline (158.917 us; speedup 1.0000x reference)
//
#include <hip/hip_runtime.h>

#define NCLS 81
#define ROW  85            // 4 loc + 81 logits
#define TPB  128           // threads per block == priors per block

// Correctly-rounded-to-f32 exp (computed in f64, ~3e-16 rel error):
// Cody-Waite 2-term ln2 reduction + degree-13 Taylor Horner + exact 2^n scale.
// Branch-free. Matches np.exp(float32) bit-for-bit except with probability
// ~5e-9 per call (f32 rounding-boundary coincidence).
__device__ __forceinline__ float exp_cr(float xf) {
    double x = (double)xf;
    x = (x < -150.0) ? -150.0 : x;                 // clamp: exp(-150) -> f32 0
    double t = x * 1.4426950408889634074;          // x * log2(e)
    double nd = rint(t);                           // v_rndne_f64
    double r = fma(nd, -6.93147180369123816490e-01, x);  // ln2_hi
    r = fma(nd, -1.90821492927058770002e-10, r);         // ln2_lo
    double p = 1.0 / 6227020800.0;                 // 1/13!
    p = fma(p, r, 1.0 / 479001600.0);
    p = fma(p, r, 1.0 / 39916800.0);
    p = fma(p, r, 1.0 / 3628800.0);
    p = fma(p, r, 1.0 / 362880.0);
    p = fma(p, r, 1.0 / 40320.0);
    p = fma(p, r, 1.0 / 5040.0);
    p = fma(p, r, 1.0 / 720.0);
    p = fma(p, r, 1.0 / 120.0);
    p = fma(p, r, 1.0 / 24.0);
    p = fma(p, r, 1.0 / 6.0);
    p = fma(p, r, 0.5);
    p = fma(p, r, 1.0);
    p = fma(p, r, 1.0);
    long long ni = (long long)nd;                  // ni in [-217, 0]
    double sc = __longlong_as_double((1023LL + ni) << 52);
    return (float)(p * sc);
}

__global__ __launch_bounds__(TPB) void ssd_decode_kernel(
    const float* __restrict__ inp,      // [N, 85]
    const float* __restrict__ priors,   // [N, 4]
    const float* __restrict__ var,      // [2]
    const float* __restrict__ thr,      // [1]
    float* __restrict__ out,            // 12N flat: boxes 4N | conf N | pred N | det 6N
    int n)
{
    __shared__ __align__(16) float lds[TPB * ROW];   // 43,520 B
    const int tid = threadIdx.x;
    const long long base = (long long)blockIdx.x * TPB;
    if (base >= n) return;

    // ---- stage TPB rows, coalesced float4 (chunk start is 16B aligned) ----
    {
        const float4* g4 = reinterpret_cast<const float4*>(inp) + base * ROW / 4;
        float4* l4 = reinterpret_cast<float4*>(lds);
        const int NV4 = TPB * ROW / 4;               // 2720
        #pragma unroll
        for (int k = 0; k < NV4 / TPB; ++k)          // 21 full rounds
            l4[k * TPB + tid] = g4[k * TPB + tid];
        const int tail = NV4 - (NV4 / TPB) * TPB;    // 32
        if (tid < tail)
            l4[(NV4 / TPB) * TPB + tid] = g4[(NV4 / TPB) * TPB + tid];
    }
    __syncthreads();

    float* row = lds + tid * ROW;    // lane t, class c -> bank (21t+c)%32: 2-way = free

    // ---- pass A: max logit (max is associative; 8-way tree) ----
    float mx[8];
    #pragma unroll
    for (int j = 0; j < 8; ++j) mx[j] = row[4 + j];
    #pragma unroll
    for (int k = 1; k < 10; ++k)
        #pragma unroll
        for (int j = 0; j < 8; ++j) mx[j] = fmaxf(mx[j], row[4 + k * 8 + j]);
    float m = fmaxf(fmaxf(fmaxf(mx[0], mx[1]), fmaxf(mx[2], mx[3])),
                    fmaxf(fmaxf(mx[4], mx[5]), fmaxf(mx[6], mx[7])));
    m = fmaxf(m, row[84]);

    // ---- pass B: e = exp(l - m), write back into LDS; numpy pairwise sum ----
    // numpy (n=81): r[j]=a[j]; for i=8..72 step 8: r[j]+=a[i+j];
    // s = ((r0+r1)+(r2+r3))+((r4+r5)+(r6+r7)); s += a[80];
    float racc[8];
    #pragma unroll
    for (int j = 0; j < 8; ++j) racc[j] = 0.0f;      // fl(0+e)=e exactly
    #pragma unroll
    for (int k = 0; k < 10; ++k)
        #pragma unroll
        for (int j = 0; j < 8; ++j) {
            float e = exp_cr(row[4 + k * 8 + j] - m);
            row[4 + k * 8 + j] = e;
            racc[j] += e;
        }
    float s = ((racc[0] + racc[1]) + (racc[2] + racc[3]))
            + ((racc[4] + racc[5]) + (racc[6] + racc[7]));
    float e80 = exp_cr(row[84] - m);
    row[84] = e80;
    s += e80;

    // ---- max prob + tie boundary ----
    // max prob = fl(1/s)  (e_max = exp(0) = 1.0 exactly).
    // fl(e/s) is monotone in e, so {e : fl(e/s)==pmax} is an f32 interval
    // containing 1.0; its width is <= ~4 ulps of e. Walk the lower edge.
    float pmax = 1.0f / s;                           // IEEE div
    float t = 1.0f;
    #pragma unroll
    for (int k = 0; k < 8; ++k) {
        float tn = __uint_as_float(__float_as_uint(t) - 1u);
        t = ((tn / s) == pmax) ? tn : t;             // idempotent once it stops
    }

    // ---- pass C: first index with fl(e/s)==pmax  <=>  first e >= t ----
    int am = 81;
    #pragma unroll
    for (int c = 80; c >= 0; --c)
        am = (row[4 + c] >= t) ? c : am;             // descending keeps FIRST

    // ---- decode box ----
    float l0 = row[0], l1 = row[1], l2 = row[2], l3 = row[3];
    float4 pr = reinterpret_cast<const float4*>(priors)[base + tid];
    float v0 = var[0], v1 = var[1];
    float cx = pr.x + l0 * v0 * pr.z;
    float cy = pr.y + l1 * v0 * pr.w;
    float w  = pr.z * exp_cr(l2 * v1);
    float h  = pr.w * exp_cr(l3 * v1);
    float x0 = cx - w * 0.5f;
    float y0 = cy - h * 0.5f;
    float x1 = x0 + w;
    float y1 = y0 + h;

    bool valid = (am > 0) && (pmax > thr[0]);

    float4 box;
    box.x = valid ? x0 : 0.0f;
    box.y = valid ? y0 : 0.0f;
    box.z = valid ? x1 : 0.0f;
    box.w = valid ? y1 : 0.0f;
    float cz = valid ? pmax : 0.0f;
    float pz = valid ? (float)(am - 1) : -1.0f;

    const long long i = base + tid;
    reinterpret_cast<float4*>(out)[i] = box;         // boxes [N,4]
    out[(long long)4 * n + i] = cz;                  // class_conf [N]
    out[(long long)5 * n + i] = pz;                  // class_pred [N] (as f32)
    float2* det2 = reinterpret_cast<float2*>(out + (long long)6 * n + i * 6);
    det2[0] = make_float2(box.x, box.y);
    det2[1] = make_float2(box.z, box.w);
    det2[2] = make_float2(cz, pz);
}

extern "C" void kernel_launch(void* const* d_in, const int* in_sizes, int n_in,
                              void* d_out, int out_size, void* d_ws, size_t ws_size,
                              hipStream_t stream)
{
    const float* inp    = (const float*)d_in[0];
    const float* priors = (const float*)d_in[1];
    const float* var    = (const float*)d_in[2];
    const float* thr    = (const float*)d_in[3];
    float* out = (float*)d_out;

    int n = in_sizes[1] / 4;              // priors has N*4 elements
    int blocks = (n + TPB - 1) / TPB;     // N = 262144 -> 2048 blocks, no tail
    ssd_decode_kernel<<<blocks, TPB, 0, stream>>>(inp, priors, var, thr, out, n);
}

// Round 5
// 149.923 us; speedup vs baseline: 1.0600x; 1.0600x over previous
//
#include <hip/hip_runtime.h>

#define NCLS 81
#define ROW  85            // 4 loc + 81 logits
#define TPB  64            // 1 wave per block; 64 priors per block
#define BLK_BYTES (TPB * ROW * 4)   // 21760 B staged per block

typedef __attribute__((address_space(3))) void*       as3_void;
typedef const __attribute__((address_space(1))) void* as1_cvoid;

// Correctly-rounded-to-f32 exp (computed in f64, ~1e-16 rel error):
// Cody-Waite 2-term ln2 reduction + degree-13 Taylor Horner + exact 2^n scale.
// Branch-free. Bit-matches np.exp->f32 (absmax 0.0 verified in round 2/4).
__device__ __forceinline__ float exp_cr(float xf) {
    double x = (double)xf;
    x = (x < -150.0) ? -150.0 : x;                 // clamp: exp(-150) -> f32 0
    double t = x * 1.4426950408889634074;          // x * log2(e)
    double nd = rint(t);                           // v_rndne_f64
    double r = fma(nd, -6.93147180369123816490e-01, x);  // ln2_hi
    r = fma(nd, -1.90821492927058770002e-10, r);         // ln2_lo
    double p = 1.0 / 6227020800.0;                 // 1/13!
    p = fma(p, r, 1.0 / 479001600.0);
    p = fma(p, r, 1.0 / 39916800.0);
    p = fma(p, r, 1.0 / 3628800.0);
    p = fma(p, r, 1.0 / 362880.0);
    p = fma(p, r, 1.0 / 40320.0);
    p = fma(p, r, 1.0 / 5040.0);
    p = fma(p, r, 1.0 / 720.0);
    p = fma(p, r, 1.0 / 120.0);
    p = fma(p, r, 1.0 / 24.0);
    p = fma(p, r, 1.0 / 6.0);
    p = fma(p, r, 0.5);
    p = fma(p, r, 1.0);
    p = fma(p, r, 1.0);
    long long ni = (long long)nd;                  // ni in [-217, 0]
    double sc = __longlong_as_double((1023LL + ni) << 52);
    return (float)(p * sc);
}

__global__ __launch_bounds__(TPB) void ssd_decode_kernel(
    const float* __restrict__ inp,      // [N, 85]
    const float* __restrict__ priors,   // [N, 4]
    const float* __restrict__ var,      // [2]
    const float* __restrict__ thr,      // [1]
    float* __restrict__ out,            // 12N flat: boxes 4N | conf N | pred N | det 6N
    int n)
{
    __shared__ __align__(16) float lds[TPB * ROW];   // 21,760 B -> 7 blocks/CU
    const int tid = threadIdx.x;
    const long long base = (long long)blockIdx.x * TPB;
    if (base >= n) return;

    // ---- stage 64 rows via async global->LDS (wave-uniform base + lane*size) ----
    // 21 x (64 lanes x 16B) = 21504 B, then 1 x (64 lanes x 4B) = 256 B. Exact.
    {
        const char* gsrc = (const char*)inp + (long long)blockIdx.x * BLK_BYTES;
        char* lbase = (char*)lds;
        #pragma unroll
        for (int k = 0; k < 21; ++k) {
            __builtin_amdgcn_global_load_lds(
                (as1_cvoid)(gsrc + k * 1024 + tid * 16),
                (as3_void)(lbase + k * 1024), 16, 0, 0);
        }
        __builtin_amdgcn_global_load_lds(
            (as1_cvoid)(gsrc + 21504 + tid * 4),
            (as3_void)(lbase + 21504), 4, 0, 0);
        asm volatile("s_waitcnt vmcnt(0)" ::: "memory");
        __builtin_amdgcn_sched_barrier(0);
    }
    __syncthreads();   // single wave: near-free; also a compiler fence

    float* row = lds + tid * ROW;    // lane t, class c -> bank (21t+c)%32: 2-way = free

    // ---- pass A: max logit (max is associative; 8-way tree) ----
    float mx[8];
    #pragma unroll
    for (int j = 0; j < 8; ++j) mx[j] = row[4 + j];
    #pragma unroll
    for (int k = 1; k < 10; ++k)
        #pragma unroll
        for (int j = 0; j < 8; ++j) mx[j] = fmaxf(mx[j], row[4 + k * 8 + j]);
    float m = fmaxf(fmaxf(fmaxf(mx[0], mx[1]), fmaxf(mx[2], mx[3])),
                    fmaxf(fmaxf(mx[4], mx[5]), fmaxf(mx[6], mx[7])));
    m = fmaxf(m, row[84]);

    // ---- pass B: e = exp(l - m), write back into LDS; numpy pairwise sum ----
    // numpy (n=81): r[j]=a[j]; for i=8..72 step 8: r[j]+=a[i+j];
    // s = ((r0+r1)+(r2+r3))+((r4+r5)+(r6+r7)); s += a[80];
    // 8 independent exp chains per k-iteration -> ILP hides the f64 FMA latency.
    float racc[8];
    #pragma unroll
    for (int j = 0; j < 8; ++j) racc[j] = 0.0f;      // fl(0+e)=e exactly
    #pragma unroll
    for (int k = 0; k < 10; ++k)
        #pragma unroll
        for (int j = 0; j < 8; ++j) {
            float e = exp_cr(row[4 + k * 8 + j] - m);
            row[4 + k * 8 + j] = e;
            racc[j] += e;
        }
    float s = ((racc[0] + racc[1]) + (racc[2] + racc[3]))
            + ((racc[4] + racc[5]) + (racc[6] + racc[7]));
    float e80 = exp_cr(row[84] - m);
    row[84] = e80;
    s += e80;

    // ---- max prob + tie boundary ----
    // max prob = fl(1/s) (e_max = exp(0) = 1.0 exactly). fl(e/s) is monotone
    // in e, so {e : fl(e/s)==pmax} is an f32 interval containing 1.0; walk
    // its lower edge (width <= ~4 ulps).
    float pmax = 1.0f / s;                           // IEEE div
    float t = 1.0f;
    #pragma unroll
    for (int k = 0; k < 8; ++k) {
        float tn = __uint_as_float(__float_as_uint(t) - 1u);
        t = ((tn / s) == pmax) ? tn : t;             // idempotent once it stops
    }

    // ---- pass C: first index with fl(e/s)==pmax  <=>  first e >= t ----
    int am = 81;
    #pragma unroll
    for (int c = 80; c >= 0; --c)
        am = (row[4 + c] >= t) ? c : am;             // descending keeps FIRST

    // ---- decode box ----
    float l0 = row[0], l1 = row[1], l2 = row[2], l3 = row[3];
    float4 pr = reinterpret_cast<const float4*>(priors)[base + tid];
    float v0 = var[0], v1 = var[1];
    float cx = pr.x + l0 * v0 * pr.z;
    float cy = pr.y + l1 * v0 * pr.w;
    float w  = pr.z * exp_cr(l2 * v1);
    float h  = pr.w * exp_cr(l3 * v1);
    float x0 = cx - w * 0.5f;
    float y0 = cy - h * 0.5f;
    float x1 = x0 + w;
    float y1 = y0 + h;

    bool valid = (am > 0) && (pmax > thr[0]);

    float4 box;
    box.x = valid ? x0 : 0.0f;
    box.y = valid ? y0 : 0.0f;
    box.z = valid ? x1 : 0.0f;
    box.w = valid ? y1 : 0.0f;
    float cz = valid ? pmax : 0.0f;
    float pz = valid ? (float)(am - 1) : -1.0f;

    const long long i = base + tid;
    reinterpret_cast<float4*>(out)[i] = box;         // boxes [N,4]
    out[(long long)4 * n + i] = cz;                  // class_conf [N]
    out[(long long)5 * n + i] = pz;                  // class_pred [N] (as f32)
    float2* det2 = reinterpret_cast<float2*>(out + (long long)6 * n + i * 6);
    det2[0] = make_float2(box.x, box.y);
    det2[1] = make_float2(box.z, box.w);
    det2[2] = make_float2(cz, pz);
}

extern "C" void kernel_launch(void* const* d_in, const int* in_sizes, int n_in,
                              void* d_out, int out_size, void* d_ws, size_t ws_size,
                              hipStream_t stream)
{
    const float* inp    = (const float*)d_in[0];
    const float* priors = (const float*)d_in[1];
    const float* var    = (const float*)d_in[2];
    const float* thr    = (const float*)d_in[3];
    float* out = (float*)d_out;

    int n = in_sizes[1] / 4;              // priors has N*4 elements
    int blocks = (n + TPB - 1) / TPB;     // 262144/64 = 4096 blocks, no tail
    ssd_decode_kernel<<<blocks, TPB, 0, stream>>>(inp, priors, var, thr, out, n);
}

// Round 6
// 144.616 us; speedup vs baseline: 1.0989x; 1.0367x over previous
//
#include <hip/hip_runtime.h>

#define NCLS 81
#define ROW  85            // 4 loc + 81 logits
#define TPB  64            // 1 wave per block; 64 priors per block
#define BLK_BYTES (TPB * ROW * 4)   // 21760 B staged per block

typedef __attribute__((address_space(3))) void*       as3_void;
typedef const __attribute__((address_space(1))) void* as1_cvoid;

// Correctly-rounded-to-f32 exp (f64 Cody-Waite + degree-13 Horner).
// Bit-matches np.exp->f32 (absmax 0.0 verified rounds 2/4/5).
// Only executed by waves containing a near-tie lane (~6 of 4096).
__device__ __forceinline__ float exp_cr(float xf) {
    double x = (double)xf;
    x = (x < -150.0) ? -150.0 : x;
    double t = x * 1.4426950408889634074;
    double nd = rint(t);
    double r = fma(nd, -6.93147180369123816490e-01, x);
    r = fma(nd, -1.90821492927058770002e-10, r);
    double p = 1.0 / 6227020800.0;
    p = fma(p, r, 1.0 / 479001600.0);
    p = fma(p, r, 1.0 / 39916800.0);
    p = fma(p, r, 1.0 / 3628800.0);
    p = fma(p, r, 1.0 / 362880.0);
    p = fma(p, r, 1.0 / 40320.0);
    p = fma(p, r, 1.0 / 5040.0);
    p = fma(p, r, 1.0 / 720.0);
    p = fma(p, r, 1.0 / 120.0);
    p = fma(p, r, 1.0 / 24.0);
    p = fma(p, r, 1.0 / 6.0);
    p = fma(p, r, 0.5);
    p = fma(p, r, 1.0);
    p = fma(p, r, 1.0);
    long long ni = (long long)nd;
    double sc = __longlong_as_double((1023LL + ni) << 52);
    return (float)(p * sc);
}

__global__ __launch_bounds__(TPB) void ssd_decode_kernel(
    const float* __restrict__ inp,      // [N, 85]
    const float* __restrict__ priors,   // [N, 4]
    const float* __restrict__ var,      // [2]
    const float* __restrict__ thr,      // [1]
    float* __restrict__ out,            // 12N flat: boxes 4N | conf N | pred N | det 6N
    int n)
{
    __shared__ __align__(16) float lds[TPB * ROW];   // 21,760 B -> 7 blocks/CU
    const int tid = threadIdx.x;
    const long long base = (long long)blockIdx.x * TPB;
    if (base >= n) return;

    // ---- stage 64 rows via async global->LDS (21x16B + 1x4B per lane) ----
    {
        const char* gsrc = (const char*)inp + (long long)blockIdx.x * BLK_BYTES;
        char* lbase = (char*)lds;
        #pragma unroll
        for (int k = 0; k < 21; ++k) {
            __builtin_amdgcn_global_load_lds(
                (as1_cvoid)(gsrc + k * 1024 + tid * 16),
                (as3_void)(lbase + k * 1024), 16, 0, 0);
        }
        __builtin_amdgcn_global_load_lds(
            (as1_cvoid)(gsrc + 21504 + tid * 4),
            (as3_void)(lbase + 21504), 4, 0, 0);
        asm volatile("s_waitcnt vmcnt(0)" ::: "memory");
        __builtin_amdgcn_sched_barrier(0);
    }
    __syncthreads();

    float* row = lds + tid * ROW;    // lane t, class c -> bank (21t+c)%32: 2-way = free

    // ---- pass A: max logit (8-way tree) ----
    float mx[8];
    #pragma unroll
    for (int j = 0; j < 8; ++j) mx[j] = row[4 + j];
    #pragma unroll
    for (int k = 1; k < 10; ++k)
        #pragma unroll
        for (int j = 0; j < 8; ++j) mx[j] = fmaxf(mx[j], row[4 + k * 8 + j]);
    float m = fmaxf(fmaxf(fmaxf(mx[0], mx[1]), fmaxf(mx[2], mx[3])),
                    fmaxf(fmaxf(mx[4], mx[5]), fmaxf(mx[6], mx[7])));
    m = fmaxf(m, row[84]);

    // ---- pass B (fast): d = l - m (bit-identical f32), candidate count,
    //      hardware-exp sum. Tie requires e >= 1-8*2^-24 i.e. d >= -4.8e-7;
    //      candidate window d >= -2^-20 gives 2x margin. ----
    int nc = 0;
    int amf = 127;
    float racc[8];
    #pragma unroll
    for (int j = 0; j < 8; ++j) racc[j] = 0.0f;
    #pragma unroll
    for (int k = 0; k < 10; ++k)
        #pragma unroll
        for (int j = 0; j < 8; ++j) {
            int c = k * 8 + j;
            float d = row[4 + c] - m;
            nc  += (d >= -9.5367431640625e-07f) ? 1 : 0;
            int cand = (d == 0.0f) ? c : 127;
            amf = (cand < amf) ? cand : amf;
            racc[j] += __expf(d);
        }
    float s1 = ((racc[0] + racc[1]) + (racc[2] + racc[3]))
             + ((racc[4] + racc[5]) + (racc[6] + racc[7]));
    {
        float d80 = row[84] - m;
        nc  += (d80 >= -9.5367431640625e-07f) ? 1 : 0;
        int cand = (d80 == 0.0f) ? 80 : 127;
        amf = (cand < amf) ? cand : amf;
        s1 += __expf(d80);
    }

    int am;
    float conf;
    if (__any(nc > 1)) {
        // ---- exact path (proven absmax 0.0): np-bitwise e, pairwise sum,
        //      IEEE-div boundary walk == first-tie argmax over probs ----
        float racx[8];
        #pragma unroll
        for (int j = 0; j < 8; ++j) racx[j] = 0.0f;
        #pragma unroll
        for (int k = 0; k < 10; ++k)
            #pragma unroll
            for (int j = 0; j < 8; ++j) {
                float e = exp_cr(row[4 + k * 8 + j] - m);
                row[4 + k * 8 + j] = e;
                racx[j] += e;
            }
        float s = ((racx[0] + racx[1]) + (racx[2] + racx[3]))
                + ((racx[4] + racx[5]) + (racx[6] + racx[7]));
        float e80 = exp_cr(row[84] - m);
        row[84] = e80;
        s += e80;

        float pmax = 1.0f / s;
        float t = 1.0f;
        #pragma unroll
        for (int k = 0; k < 8; ++k) {
            float tn = __uint_as_float(__float_as_uint(t) - 1u);
            t = ((tn / s) == pmax) ? tn : t;
        }
        am = 81;
        #pragma unroll
        for (int c = 80; c >= 0; --c)
            am = (row[4 + c] >= t) ? c : am;
        conf = pmax;
    } else {
        am = amf;
        conf = 1.0f / s1;
    }

    // ---- decode box (2% threshold: hardware exp is plenty) ----
    float l0 = row[0], l1 = row[1], l2 = row[2], l3 = row[3];
    float4 pr = reinterpret_cast<const float4*>(priors)[base + tid];
    float v0 = var[0], v1 = var[1];
    float cx = pr.x + l0 * v0 * pr.z;
    float cy = pr.y + l1 * v0 * pr.w;
    float w  = pr.z * __expf(l2 * v1);
    float h  = pr.w * __expf(l3 * v1);
    float x0 = cx - w * 0.5f;
    float y0 = cy - h * 0.5f;
    float x1 = x0 + w;
    float y1 = y0 + h;

    bool valid = (am > 0) && (conf > thr[0]);

    float4 box;
    box.x = valid ? x0 : 0.0f;
    box.y = valid ? y0 : 0.0f;
    box.z = valid ? x1 : 0.0f;
    box.w = valid ? y1 : 0.0f;
    float cz = valid ? conf : 0.0f;
    float pz = valid ? (float)(am - 1) : -1.0f;

    const long long i = base + tid;
    reinterpret_cast<float4*>(out)[i] = box;         // boxes [N,4]
    out[(long long)4 * n + i] = cz;                  // class_conf [N]
    out[(long long)5 * n + i] = pz;                  // class_pred [N] (as f32)
    float2* det2 = reinterpret_cast<float2*>(out + (long long)6 * n + i * 6);
    det2[0] = make_float2(box.x, box.y);
    det2[1] = make_float2(box.z, box.w);
    det2[2] = make_float2(cz, pz);
}

extern "C" void kernel_launch(void* const* d_in, const int* in_sizes, int n_in,
                              void* d_out, int out_size, void* d_ws, size_t ws_size,
                              hipStream_t stream)
{
    const float* inp    = (const float*)d_in[0];
    const float* priors = (const float*)d_in[1];
    const float* var    = (const float*)d_in[2];
    const float* thr    = (const float*)d_in[3];
    float* out = (float*)d_out;

    int n = in_sizes[1] / 4;              // priors has N*4 elements
    int blocks = (n + TPB - 1) / TPB;     // 262144/64 = 4096 blocks, no tail
    ssd_decode_kernel<<<blocks, TPB, 0, stream>>>(inp, priors, var, thr, out, n);
}

// Round 8
// 141.931 us; speedup vs baseline: 1.1197x; 1.0189x over previous
//
#include <hip/hip_runtime.h>

#define NCLS 81
#define ROW  85            // 4 loc + 81 logits
#define TPB  64            // 1 wave per block; 64 priors per block
#define BLK_BYTES (TPB * ROW * 4)   // 21760 B staged per block

typedef __attribute__((address_space(3))) void*       as3_void;
typedef const __attribute__((address_space(1))) void* as1_cvoid;

// Correctly-rounded-to-f32 exp (f64 Cody-Waite + degree-13 Horner).
// Bit-matches np.exp->f32 (absmax 0.0 verified rounds 2/4/5/6).
// Only executed by waves containing a near-tie lane (~6% of waves).
__device__ __forceinline__ float exp_cr(float xf) {
    double x = (double)xf;
    x = (x < -150.0) ? -150.0 : x;
    double t = x * 1.4426950408889634074;
    double nd = rint(t);
    double r = fma(nd, -6.93147180369123816490e-01, x);
    r = fma(nd, -1.90821492927058770002e-10, r);
    double p = 1.0 / 6227020800.0;
    p = fma(p, r, 1.0 / 479001600.0);
    p = fma(p, r, 1.0 / 39916800.0);
    p = fma(p, r, 1.0 / 3628800.0);
    p = fma(p, r, 1.0 / 362880.0);
    p = fma(p, r, 1.0 / 40320.0);
    p = fma(p, r, 1.0 / 5040.0);
    p = fma(p, r, 1.0 / 720.0);
    p = fma(p, r, 1.0 / 120.0);
    p = fma(p, r, 1.0 / 24.0);
    p = fma(p, r, 1.0 / 6.0);
    p = fma(p, r, 0.5);
    p = fma(p, r, 1.0);
    p = fma(p, r, 1.0);
    long long ni = (long long)nd;
    double sc = __longlong_as_double((1023LL + ni) << 52);
    return (float)(p * sc);
}

__global__ __launch_bounds__(TPB) void ssd_decode_kernel(
    const float* __restrict__ inp,      // [N, 85]
    const float* __restrict__ priors,   // [N, 4]
    const float* __restrict__ var,      // [2]
    const float* __restrict__ thr,      // [1]
    float* __restrict__ out,            // 12N flat: boxes 4N | conf N | pred N | det 6N
    int n)
{
    __shared__ __align__(16) float lds[TPB * ROW];   // 21,760 B -> 7 blocks/CU
    const int tid = threadIdx.x;
    const long long base = (long long)blockIdx.x * TPB;
    if (base >= n) return;

    // ---- stage 64 rows via async global->LDS (21x16B + 1x4B per lane) ----
    {
        const char* gsrc = (const char*)inp + (long long)blockIdx.x * BLK_BYTES;
        char* lbase = (char*)lds;
        #pragma unroll
        for (int k = 0; k < 21; ++k) {
            __builtin_amdgcn_global_load_lds(
                (as1_cvoid)(gsrc + k * 1024 + tid * 16),
                (as3_void)(lbase + k * 1024), 16, 0, 0);
        }
        __builtin_amdgcn_global_load_lds(
            (as1_cvoid)(gsrc + 21504 + tid * 4),
            (as3_void)(lbase + 21504), 4, 0, 0);
        asm volatile("s_waitcnt vmcnt(0)" ::: "memory");
        __builtin_amdgcn_sched_barrier(0);
    }
    __syncthreads();

    float* row = lds + tid * ROW;    // lane t, word w -> bank (21t+w)%32: 2-way = free

    // ---- hoist the whole row into registers: 85 INDEPENDENT ds_read_b32,
    //      batched by the compiler, drained once. All passes below run
    //      register-only (round 5/6 chained ds_read latency per element
    //      at ~1.2 waves/SIMD -> ~95% stall; this removes that). ----
    float lg[ROW];
    #pragma unroll
    for (int k = 0; k < ROW; ++k) lg[k] = row[k];

    // ---- pass A: max logit (8-way tree, regs) ----
    float mx[8];
    #pragma unroll
    for (int j = 0; j < 8; ++j) mx[j] = lg[4 + j];
    #pragma unroll
    for (int k = 1; k < 10; ++k)
        #pragma unroll
        for (int j = 0; j < 8; ++j) mx[j] = fmaxf(mx[j], lg[4 + k * 8 + j]);
    float m = fmaxf(fmaxf(fmaxf(mx[0], mx[1]), fmaxf(mx[2], mx[3])),
                    fmaxf(fmaxf(mx[4], mx[5]), fmaxf(mx[6], mx[7])));
    m = fmaxf(m, lg[84]);

    // ---- pass B (fast, regs): d = l - m (bit-identical f32), candidate
    //      count, hardware-exp sum. Tie requires e >= 1-8*2^-24 i.e.
    //      d >= -4.8e-7; window d >= -2^-20 gives 2x margin. ----
    int nc = 0;
    int amf = 127;
    float racc[8];
    #pragma unroll
    for (int j = 0; j < 8; ++j) racc[j] = 0.0f;
    #pragma unroll
    for (int k = 0; k < 10; ++k)
        #pragma unroll
        for (int j = 0; j < 8; ++j) {
            int c = k * 8 + j;
            float d = lg[4 + c] - m;
            nc  += (d >= -9.5367431640625e-07f) ? 1 : 0;
            int cand = (d == 0.0f) ? c : 127;
            amf = (cand < amf) ? cand : amf;
            racc[j] += __expf(d);
        }
    float s1 = ((racc[0] + racc[1]) + (racc[2] + racc[3]))
             + ((racc[4] + racc[5]) + (racc[6] + racc[7]));
    {
        float d80 = lg[84] - m;
        nc  += (d80 >= -9.5367431640625e-07f) ? 1 : 0;
        int cand = (d80 == 0.0f) ? 80 : 127;
        amf = (cand < amf) ? cand : amf;
        s1 += __expf(d80);
    }

    int am;
    float conf;
    if (__any(nc > 1)) {
        // ---- exact fallback (cold, proven absmax 0.0): np-bitwise e via
        //      LDS row, pairwise sum, IEEE-div boundary walk == first-tie
        //      argmax over probs. lg[] is dead here -> regs reused. ----
        float racx[8];
        #pragma unroll
        for (int j = 0; j < 8; ++j) racx[j] = 0.0f;
        #pragma unroll
        for (int k = 0; k < 10; ++k)
            #pragma unroll
            for (int j = 0; j < 8; ++j) {
                float e = exp_cr(row[4 + k * 8 + j] - m);
                row[4 + k * 8 + j] = e;
                racx[j] += e;
            }
        float s = ((racx[0] + racx[1]) + (racx[2] + racx[3]))
                + ((racx[4] + racx[5]) + (racx[6] + racx[7]));
        float e80 = exp_cr(row[84] - m);
        row[84] = e80;
        s += e80;

        float pmax = 1.0f / s;
        float t = 1.0f;
        #pragma unroll
        for (int k = 0; k < 8; ++k) {
            float tn = __uint_as_float(__float_as_uint(t) - 1u);
            t = ((tn / s) == pmax) ? tn : t;
        }
        am = 81;
        #pragma unroll
        for (int c = 80; c >= 0; --c)
            am = (row[4 + c] >= t) ? c : am;
        conf = pmax;
    } else {
        am = amf;
        conf = 1.0f / s1;
    }

    // ---- decode box (2% threshold: hardware exp is plenty) ----
    float l0 = lg[0], l1 = lg[1], l2 = lg[2], l3 = lg[3];
    float4 pr = reinterpret_cast<const float4*>(priors)[base + tid];
    float v0 = var[0], v1 = var[1];
    float cx = pr.x + l0 * v0 * pr.z;
    float cy = pr.y + l1 * v0 * pr.w;
    float w  = pr.z * __expf(l2 * v1);
    float h  = pr.w * __expf(l3 * v1);
    float x0 = cx - w * 0.5f;
    float y0 = cy - h * 0.5f;
    float x1 = x0 + w;
    float y1 = y0 + h;

    bool valid = (am > 0) && (conf > thr[0]);

    float4 box;
    box.x = valid ? x0 : 0.0f;
    box.y = valid ? y0 : 0.0f;
    box.z = valid ? x1 : 0.0f;
    box.w = valid ? y1 : 0.0f;
    float cz = valid ? conf : 0.0f;
    float pz = valid ? (float)(am - 1) : -1.0f;

    const long long i = base + tid;
    reinterpret_cast<float4*>(out)[i] = box;         // boxes [N,4]
    out[(long long)4 * n + i] = cz;                  // class_conf [N]
    out[(long long)5 * n + i] = pz;                  // class_pred [N] (as f32)
    float2* det2 = reinterpret_cast<float2*>(out + (long long)6 * n + i * 6);
    det2[0] = make_float2(box.x, box.y);
    det2[1] = make_float2(box.z, box.w);
    det2[2] = make_float2(cz, pz);
}

extern "C" void kernel_launch(void* const* d_in, const int* in_sizes, int n_in,
                              void* d_out, int out_size, void* d_ws, size_t ws_size,
                              hipStream_t stream)
{
    const float* inp    = (const float*)d_in[0];
    const float* priors = (const float*)d_in[1];
    const float* var    = (const float*)d_in[2];
    const float* thr    = (const float*)d_in[3];
    float* out = (float*)d_out;

    int n = in_sizes[1] / 4;              // priors has N*4 elements
    int blocks = (n + TPB - 1) / TPB;     // 262144/64 = 4096 blocks, no tail
    ssd_decode_kernel<<<blocks, TPB, 0, stream>>>(inp, priors, var, thr, out, n);
}